// Round 1
// 172.537 us; speedup vs baseline: 1.2377x; 1.2377x over previous
//
#include <hip/hip_runtime.h>
#include <math.h>

#define TOKENS 32768
#define RDIM 512
#define NEXP 64
#define NK 256
#define LDK 136            // 128-k chunk + 8 pad (ushorts); 272B rows -> 2-way banks (free), 16B aligned
#define TAU 4.0e-3f        // top-2/3 boundary guard band (~60x worst-case bf16x3 logit error)

typedef unsigned short u16;
typedef float f32x4 __attribute__((ext_vector_type(4)));
typedef short s16x8 __attribute__((ext_vector_type(8)));

#define MFMA_B16(a, b, c) __builtin_amdgcn_mfma_f32_16x16x32_bf16(a, b, c, 0, 0, 0)

// Truncating hi/lo bf16 split of 2 floats, packed low|high into uints (k-ascending in memory).
// Dropped ll-term error <= 2^-14 rel per product -> logit err ~6e-5, covered by TAU guard.
__device__ __forceinline__ void split_pack(float4 v, unsigned& h01, unsigned& h23,
                                           unsigned& l01, unsigned& l23) {
    unsigned u0 = __float_as_uint(v.x), u1 = __float_as_uint(v.y);
    unsigned u2 = __float_as_uint(v.z), u3 = __float_as_uint(v.w);
    float r0 = v.x - __uint_as_float(u0 & 0xFFFF0000u);
    float r1 = v.y - __uint_as_float(u1 & 0xFFFF0000u);
    float r2 = v.z - __uint_as_float(u2 & 0xFFFF0000u);
    float r3 = v.w - __uint_as_float(u3 & 0xFFFF0000u);
    h01 = (u0 >> 16) | (u1 & 0xFFFF0000u);
    h23 = (u2 >> 16) | (u3 & 0xFFFF0000u);
    l01 = (__float_as_uint(r0) >> 16) | (__float_as_uint(r1) & 0xFFFF0000u);
    l23 = (__float_as_uint(r2) >> 16) | (__float_as_uint(r3) & 0xFFFF0000u);
}

// ---------------- Kernel A: expert centroids via sign-LUT bit tricks (unchanged) ----------------
__global__ __launch_bounds__(256) void centroid_kernel(
    const float* __restrict__ atoms,
    const float* __restrict__ cw,
    const float* __restrict__ cl,
    float* __restrict__ cent,
    float* __restrict__ aux_sum,
    unsigned* __restrict__ aux_cnt)
{
    __shared__ unsigned pack[NK];
    const int e    = blockIdx.x >> 1;
    const int half = blockIdx.x & 1;
    const int tid  = threadIdx.x;

    if (blockIdx.x == 0 && tid < 64) { aux_sum[tid] = 0.f; aux_cnt[tid] = 0u; }

    {   // one k per thread (256 threads == NK)
        const int k = tid;
        unsigned u = 0;
        float w3[3];
        #pragma unroll
        for (int xx = 0; xx < 3; ++xx) {
            const float* cp = cl + ((((size_t)e * NK + k) * 3 + xx) << 4);
            float v[16];
            *(float4*)(v + 0)  = *(const float4*)(cp + 0);
            *(float4*)(v + 4)  = *(const float4*)(cp + 4);
            *(float4*)(v + 8)  = *(const float4*)(cp + 8);
            *(float4*)(v + 12) = *(const float4*)(cp + 12);
            float best = v[0]; int bi = 0;
            #pragma unroll
            for (int a = 1; a < 16; ++a) {          // strict > keeps first max (jnp.argmax)
                if (v[a] > best) { best = v[a]; bi = a; }
            }
            u |= (unsigned)bi << (4 * xx);
            w3[xx] = cw[((size_t)e * NK + k) * 3 + xx];
        }
        unsigned lut = 0;
        #pragma unroll
        for (int c = 0; c < 8; ++c) {
            float val = ((c & 1) ? -w3[0] : w3[0])
                      + ((c & 2) ? -w3[1] : w3[1])
                      + ((c & 4) ? -w3[2] : w3[2]);
            lut |= (val < 0.f ? 1u : 0u) << c;
        }
        pack[k] = u | (lut << 16);
    }

    const int r = half * 256 + tid;
    unsigned B0 = 0;
    #pragma unroll
    for (int a = 0; a < 16; ++a)
        B0 |= (atoms[((size_t)e * 16 + a) * RDIM + r] < 0.f ? 1u : 0u) << a;
    __syncthreads();

    int n0 = 0;
    for (int k = 0; k < NK; ++k) {
        unsigned u  = pack[k];
        unsigned i0 = u & 15u, i1 = (u >> 4) & 15u, i2 = (u >> 8) & 15u;
        unsigned c0 = ((B0 >> i0) & 1u) | (((B0 >> i1) & 1u) << 1) | (((B0 >> i2) & 1u) << 2);
        n0 += (u >> (16 + c0)) & 1u;
    }
    cent[(size_t)e * RDIM + r] = 1.f - (float)n0 * (1.f / 128.f);
}

// ---------------- Kernel B: bf16 hi/lo 3-pass MFMA GEMM + fused MoE epilogue ----------------
// Block = 64 tokens x 64 experts, 4 waves, each wave owns 16 tokens x all 64 experts.
// K staged in 4 chunks of 128. x/w converted on the fly to bf16 hi+lo planes in LDS
// ([64][136] ushort, 272B rows: ds_read_b128 frags are 2-way bank aliased = free).
// mfma_f32_16x16x32_bf16: A row = lane&15 (token), B row = lane&15 (expert, B^T layout),
// k = (lane>>4)*8 + j; C: col = lane&15, row = (lane>>4)*4 + reg (m89-verified mapping).
__global__ __launch_bounds__(256) void moe_main(
    const float* __restrict__ x,
    const float* __restrict__ w,
    const float* __restrict__ cent,
    float* __restrict__ out,
    float* __restrict__ aux_sum,
    unsigned* __restrict__ aux_cnt)
{
    __shared__ f32x4 smem4[4352];          // 69632 B = 4 planes of 64x136 ushort
    u16* xhi = (u16*)smem4;
    u16* xlo = xhi + 64 * LDK;
    u16* whi = xhi + 2 * 64 * LDK;
    u16* wlo = xhi + 3 * 64 * LDK;
    float* P = (float*)smem4;              // logit plane overlay [64][66] (16.9KB, fits in xhi)
    __shared__ float s_aux[64];
    __shared__ unsigned s_cnt[64];

    const int tid  = threadIdx.x;
    const int lane = tid & 63;
    const int wave = tid >> 6;
    const int tok0 = blockIdx.x * 64;
    const int l15  = lane & 15;
    const int kgrp = (lane >> 4) << 3;     // 0,8,16,24

    if (tid < 64) { s_aux[tid] = 0.f; s_cnt[tid] = 0u; }

    f32x4 acc[4];
    #pragma unroll
    for (int nt = 0; nt < 4; ++nt) acc[nt] = (f32x4){0.f, 0.f, 0.f, 0.f};

    // staging map: thread covers rows {row0, row0+8, ..., row0+56}, 16 floats each at kq4
    const int kq4  = (tid & 31) << 2;      // float offset within the 128-wide chunk
    const int row0 = tid >> 5;             // 0..7
    const float* xg = x + (size_t)(tok0 + row0) * RDIM + kq4;
    const float* wg = w + (size_t)row0 * RDIM + kq4;
    const int ldsoff = row0 * LDK + kq4;   // ushort offset; row j adds 8*LDK

    float4 xr[8], wr[8];
    #pragma unroll
    for (int j = 0; j < 8; ++j) {          // prefetch chunk 0
        xr[j] = *(const float4*)(xg + (size_t)j * 8 * RDIM);
        wr[j] = *(const float4*)(wg + (size_t)j * 8 * RDIM);
    }

    const int arow = (wave << 4) + l15;

    for (int c = 0; c < 4; ++c) {
        __syncthreads();                   // previous chunk's frag reads done
        #pragma unroll
        for (int j = 0; j < 8; ++j) {
            unsigned h01, h23, l01, l23;
            split_pack(xr[j], h01, h23, l01, l23);
            *(uint2*)&xhi[ldsoff + j * 8 * LDK] = make_uint2(h01, h23);
            *(uint2*)&xlo[ldsoff + j * 8 * LDK] = make_uint2(l01, l23);
            split_pack(wr[j], h01, h23, l01, l23);
            *(uint2*)&whi[ldsoff + j * 8 * LDK] = make_uint2(h01, h23);
            *(uint2*)&wlo[ldsoff + j * 8 * LDK] = make_uint2(l01, l23);
        }
        __syncthreads();
        if (c < 3) {                       // prefetch next chunk; hides under MFMA phase
            const int o = (c + 1) * 128;
            #pragma unroll
            for (int j = 0; j < 8; ++j) {
                xr[j] = *(const float4*)(xg + o + (size_t)j * 8 * RDIM);
                wr[j] = *(const float4*)(wg + o + (size_t)j * 8 * RDIM);
            }
        }
        #pragma unroll
        for (int s = 0; s < 4; ++s) {      // 4 K32 steps per chunk
            const int kb = s * 32 + kgrp;
            s16x8 ah = *(const s16x8*)&xhi[arow * LDK + kb];
            s16x8 al = *(const s16x8*)&xlo[arow * LDK + kb];
            #pragma unroll
            for (int nt = 0; nt < 4; ++nt) {
                const int brow = (nt << 4) + l15;
                s16x8 bh = *(const s16x8*)&whi[brow * LDK + kb];
                s16x8 bl = *(const s16x8*)&wlo[brow * LDK + kb];
                acc[nt] = MFMA_B16(ah, bh, acc[nt]);   // hi*hi
                acc[nt] = MFMA_B16(ah, bl, acc[nt]);   // hi*lo
                acc[nt] = MFMA_B16(al, bh, acc[nt]);   // lo*hi
            }
        }
    }

    // ---- logits to LDS plane [64 tok][66] (overlay on staging) ----
    __syncthreads();
    #pragma unroll
    for (int nt = 0; nt < 4; ++nt)
        #pragma unroll
        for (int i = 0; i < 4; ++i)
            P[((wave << 4) + ((lane >> 4) << 2) + i) * 66 + nt * 16 + l15] = acc[nt][i];
    __syncthreads();

    // ---- per-token epilogue: wave handles 16 tokens, lane = expert ----
    float regsum = 0.f;
    int   regcnt = 0;
    const int e = lane;
    for (int s2 = 0; s2 < 16; ++s2) {
        const int tt = (wave << 4) + s2;
        const float val = P[tt * 66 + e];

        // top-1 with lower-index tie-break (matches lax.top_k)
        float m1 = val; int i1 = e;
        #pragma unroll
        for (int off = 32; off; off >>= 1) {
            float ov = __shfl_xor(m1, off);
            int   oi = __shfl_xor(i1, off);
            if (ov > m1 || (ov == m1 && oi < i1)) { m1 = ov; i1 = oi; }
        }
        // top-2
        float m2 = (e == i1) ? -INFINITY : val; int i2 = e;
        #pragma unroll
        for (int off = 32; off; off >>= 1) {
            float ov = __shfl_xor(m2, off);
            int   oi = __shfl_xor(i2, off);
            if (ov > m2 || (ov == m2 && oi < i2)) { m2 = ov; i2 = oi; }
        }
        // top-3 (for the selection guard band)
        float m3 = (e == i1 || e == i2) ? -INFINITY : val; int i3 = e;
        #pragma unroll
        for (int off = 32; off; off >>= 1) {
            float ov = __shfl_xor(m3, off);
            int   oi = __shfl_xor(i3, off);
            if (ov > m3 || (ov == m3 && oi < i3)) { m3 = ov; i3 = oi; }
        }

        float g1v = m1, g2v = m2; int e1 = i1, e2 = i2;
        if (m2 - m3 < TAU) {
            // near top-2/3 boundary: exact f32 re-rank of the 3 candidates (wave-uniform, rare)
            const float* xrow = x + (size_t)(tok0 + tt) * RDIM + e * 8;   // lane covers k=e*8..e*8+7
            float4 a0 = *(const float4*)(xrow);
            float4 a1 = *(const float4*)(xrow + 4);
            float d[3]; int id3[3] = { i1, i2, i3 };
            #pragma unroll
            for (int j = 0; j < 3; ++j) {
                const float* wrow = w + (size_t)id3[j] * RDIM + e * 8;
                float4 b0 = *(const float4*)(wrow);
                float4 b1 = *(const float4*)(wrow + 4);
                float p = a0.x * b0.x;
                p = fmaf(a0.y, b0.y, p); p = fmaf(a0.z, b0.z, p); p = fmaf(a0.w, b0.w, p);
                p = fmaf(a1.x, b1.x, p); p = fmaf(a1.y, b1.y, p);
                p = fmaf(a1.z, b1.z, p); p = fmaf(a1.w, b1.w, p);
                #pragma unroll
                for (int off = 32; off; off >>= 1) p += __shfl_xor(p, off);
                d[j] = p;
            }
            int b = 0;
            if (d[1] > d[0] || (d[1] == d[0] && id3[1] < id3[0])) b = 1;
            if (d[2] > d[b] || (d[2] == d[b] && id3[2] < id3[b])) b = 2;
            int sec;
            if (b == 0)      sec = (d[1] > d[2] || (d[1] == d[2] && id3[1] < id3[2])) ? 1 : 2;
            else if (b == 1) sec = (d[0] > d[2] || (d[0] == d[2] && id3[0] < id3[2])) ? 0 : 2;
            else             sec = (d[0] > d[1] || (d[0] == d[1] && id3[0] < id3[1])) ? 0 : 1;
            g1v = d[b];   e1 = id3[b];
            g2v = d[sec]; e2 = id3[sec];
        }

        // full softmax (aux) — shift-invariant in m1
        const float ex = expf(val - m1);
        float Z = ex;
        #pragma unroll
        for (int off = 32; off; off >>= 1) Z += __shfl_xor(Z, off);
        regsum += ex / Z;
        regcnt += (ex > 0.f) ? 1 : 0;

        // normalized top-2 gates: g1 = 1/(1+exp(l2-l1))
        const float ed  = expf(g2v - g1v);
        const float inv = 1.f / (1.f + ed);
        const float g1 = inv, g2 = ed * inv;

        const float4* c1 = (const float4*)(cent + (size_t)e1 * RDIM);
        const float4* c2 = (const float4*)(cent + (size_t)e2 * RDIM);
        float4* op = (float4*)(out + (size_t)(tok0 + tt) * RDIM);
        float4 A0 = c1[e],      Bb0 = c2[e];
        float4 A1 = c1[e + 64], Bb1 = c2[e + 64];
        float4 o0, o1;
        o0.x = fmaf(g1, A0.x, g2 * Bb0.x); o0.y = fmaf(g1, A0.y, g2 * Bb0.y);
        o0.z = fmaf(g1, A0.z, g2 * Bb0.z); o0.w = fmaf(g1, A0.w, g2 * Bb0.w);
        o1.x = fmaf(g1, A1.x, g2 * Bb1.x); o1.y = fmaf(g1, A1.y, g2 * Bb1.y);
        o1.z = fmaf(g1, A1.z, g2 * Bb1.z); o1.w = fmaf(g1, A1.w, g2 * Bb1.w);
        op[e]      = o0;
        op[e + 64] = o1;
    }

    atomicAdd(&s_aux[e], regsum);
    atomicAdd(&s_cnt[e], (unsigned)regcnt);
    __syncthreads();
    if (tid < 64) {
        atomicAdd(aux_sum + tid, s_aux[tid]);
        atomicAdd(aux_cnt + tid, s_cnt[tid]);
    }
}

// ---------------- Kernel C: aux loss finalize ----------------
__global__ __launch_bounds__(64) void aux_kernel(
    const float* __restrict__ sums,
    const unsigned* __restrict__ cnts,
    float* __restrict__ out_aux)
{
    const int e = threadIdx.x;
    float v = (sums[e] * (1.f / (float)TOKENS)) * ((float)cnts[e] * (1.f / (float)TOKENS));
    #pragma unroll
    for (int off = 32; off; off >>= 1) v += __shfl_xor(v, off);
    if (e == 0) out_aux[0] = (float)NEXP * v;
}

extern "C" void kernel_launch(void* const* d_in, const int* in_sizes, int n_in,
                              void* d_out, int out_size, void* d_ws, size_t ws_size,
                              hipStream_t stream) {
    const float* x     = (const float*)d_in[0];  // (8,4096,512)
    const float* rw    = (const float*)d_in[1];  // (64,512)
    const float* atoms = (const float*)d_in[2];  // (64,16,512)
    const float* cwts  = (const float*)d_in[3];  // (64,256,3)
    const float* clog  = (const float*)d_in[4];  // (64,256,3,16)
    float* out = (float*)d_out;

    float*    aux_sum = (float*)d_ws;                       // 64 floats
    unsigned* aux_cnt = (unsigned*)((char*)d_ws + 256);     // 64 uints
    float*    cent    = (float*)((char*)d_ws + 512);        // 64*512 floats

    centroid_kernel<<<128, 256, 0, stream>>>(atoms, cwts, clog, cent, aux_sum, aux_cnt);
    moe_main<<<512, 256, 0, stream>>>(x, rw, cent, out, aux_sum, aux_cnt);
    aux_kernel<<<1, 64, 0, stream>>>(aux_sum, aux_cnt, out + (size_t)TOKENS * RDIM);
}

// Round 2
// 163.502 us; speedup vs baseline: 1.3061x; 1.0553x over previous
//
#include <hip/hip_runtime.h>
#include <math.h>

#define TOKENS 32768
#define RDIM 512
#define NEXP 64
#define NK 256
#define LDK 136            // 128-k chunk + 8 pad (ushorts); 272B rows -> 2-way banks (free), 16B aligned
#define PSTR 67            // logit plane row stride (words); 67 coprime 32 -> 2-way column reads
#define TAU 4.0e-3f        // top-2/3 boundary guard band (~60x worst-case bf16x3 logit error)

typedef unsigned short u16;
typedef float f32x4 __attribute__((ext_vector_type(4)));
typedef short s16x8 __attribute__((ext_vector_type(8)));

#define MFMA_B16(a, b, c) __builtin_amdgcn_mfma_f32_16x16x32_bf16(a, b, c, 0, 0, 0)

// Truncating hi/lo bf16 split of 4 floats, packed pairwise into uints (k-ascending).
__device__ __forceinline__ void split_pack(float4 v, unsigned& h01, unsigned& h23,
                                           unsigned& l01, unsigned& l23) {
    unsigned u0 = __float_as_uint(v.x), u1 = __float_as_uint(v.y);
    unsigned u2 = __float_as_uint(v.z), u3 = __float_as_uint(v.w);
    float r0 = v.x - __uint_as_float(u0 & 0xFFFF0000u);
    float r1 = v.y - __uint_as_float(u1 & 0xFFFF0000u);
    float r2 = v.z - __uint_as_float(u2 & 0xFFFF0000u);
    float r3 = v.w - __uint_as_float(u3 & 0xFFFF0000u);
    h01 = (u0 >> 16) | (u1 & 0xFFFF0000u);
    h23 = (u2 >> 16) | (u3 & 0xFFFF0000u);
    l01 = (__float_as_uint(r0) >> 16) | (__float_as_uint(r1) & 0xFFFF0000u);
    l23 = (__float_as_uint(r2) >> 16) | (__float_as_uint(r3) & 0xFFFF0000u);
}

// ---------------- Kernel A: expert centroids via sign-LUT bit tricks (unchanged) ----------------
__global__ __launch_bounds__(256) void centroid_kernel(
    const float* __restrict__ atoms,
    const float* __restrict__ cw,
    const float* __restrict__ cl,
    float* __restrict__ cent,
    float* __restrict__ aux_sum,
    unsigned* __restrict__ aux_cnt)
{
    __shared__ unsigned pack[NK];
    const int e    = blockIdx.x >> 1;
    const int half = blockIdx.x & 1;
    const int tid  = threadIdx.x;

    if (blockIdx.x == 0 && tid < 64) { aux_sum[tid] = 0.f; aux_cnt[tid] = 0u; }

    {   // one k per thread (256 threads == NK)
        const int k = tid;
        unsigned u = 0;
        float w3[3];
        #pragma unroll
        for (int xx = 0; xx < 3; ++xx) {
            const float* cp = cl + ((((size_t)e * NK + k) * 3 + xx) << 4);
            float v[16];
            *(float4*)(v + 0)  = *(const float4*)(cp + 0);
            *(float4*)(v + 4)  = *(const float4*)(cp + 4);
            *(float4*)(v + 8)  = *(const float4*)(cp + 8);
            *(float4*)(v + 12) = *(const float4*)(cp + 12);
            float best = v[0]; int bi = 0;
            #pragma unroll
            for (int a = 1; a < 16; ++a) {          // strict > keeps first max (jnp.argmax)
                if (v[a] > best) { best = v[a]; bi = a; }
            }
            u |= (unsigned)bi << (4 * xx);
            w3[xx] = cw[((size_t)e * NK + k) * 3 + xx];
        }
        unsigned lut = 0;
        #pragma unroll
        for (int c = 0; c < 8; ++c) {
            float val = ((c & 1) ? -w3[0] : w3[0])
                      + ((c & 2) ? -w3[1] : w3[1])
                      + ((c & 4) ? -w3[2] : w3[2]);
            lut |= (val < 0.f ? 1u : 0u) << c;
        }
        pack[k] = u | (lut << 16);
    }

    const int r = half * 256 + tid;
    unsigned B0 = 0;
    #pragma unroll
    for (int a = 0; a < 16; ++a)
        B0 |= (atoms[((size_t)e * 16 + a) * RDIM + r] < 0.f ? 1u : 0u) << a;
    __syncthreads();

    int n0 = 0;
    for (int k = 0; k < NK; ++k) {
        unsigned u  = pack[k];
        unsigned i0 = u & 15u, i1 = (u >> 4) & 15u, i2 = (u >> 8) & 15u;
        unsigned c0 = ((B0 >> i0) & 1u) | (((B0 >> i1) & 1u) << 1) | (((B0 >> i2) & 1u) << 2);
        n0 += (u >> (16 + c0)) & 1u;
    }
    cent[(size_t)e * RDIM + r] = 1.f - (float)n0 * (1.f / 128.f);
}

// ---------------- Kernel B: bf16 hi/lo 3-pass MFMA GEMM + shuffle-free MoE epilogue ----------
// 512 threads = 8 waves, tile 64 tok x 64 exp (grid 512 = 2 blocks/CU, 4 waves/SIMD).
// Wave (tokG=w>>1, expG=w&1) owns 16 tok x 32 exp. Same verified MFMA fragment mapping:
// A row=l15(token), B row=l15(expert), k=(lane>>4)*8+j; C col=lane&15, row=(lane>>4)*4+i.
__global__ __launch_bounds__(512, 4) void moe_main(
    const float* __restrict__ x,
    const float* __restrict__ w,
    const float* __restrict__ cent,
    float* __restrict__ out,
    float* __restrict__ aux_sum,
    unsigned* __restrict__ aux_cnt)
{
    __shared__ f32x4 smem4[4352];          // 69632 B = 4 planes of 64x136 ushort
    u16* xhi = (u16*)smem4;
    u16* xlo = xhi + 64 * LDK;
    u16* whi = xhi + 2 * 64 * LDK;
    u16* wlo = xhi + 3 * 64 * LDK;
    // epilogue overlays (start at word 0; staging is dead by then)
    float* P     = (float*)smem4;          // [64][PSTR] logits -> probs in place
    float* candv = P + 64 * PSTR;          // [64][25] (8 slices x top-3, padded stride)
    int*   candi = (int*)(candv + 64 * 25);
    float* qsum  = (float*)(candi + 64 * 25);   // [64][9]
    float* gateL = qsum + 64 * 9;          // [64][4]: g1,g2,bitcast(e1),bitcast(e2)
    __shared__ float s_aux[64];
    __shared__ unsigned s_cnt[64];

    const int tid  = threadIdx.x;
    const int lane = tid & 63;
    const int wave = tid >> 6;
    const int l15  = lane & 15;
    const int kgrp = (lane >> 4) << 3;     // 0,8,16,24
    const int tok0 = blockIdx.x * 64;
    const int tokG = wave >> 1;            // 0..3
    const int expG = wave & 1;             // 0..1

    if (tid < 64) { s_aux[tid] = 0.f; s_cnt[tid] = 0u; }

    f32x4 acc[2];
    acc[0] = (f32x4){0.f,0.f,0.f,0.f};
    acc[1] = (f32x4){0.f,0.f,0.f,0.f};

    // staging: 512 threads cover a 64-row x 128-float chunk; thread rows row0+16j
    const int kq4  = (tid & 31) << 2;      // float offset 0..124
    const int row0 = tid >> 5;             // 0..15
    const float* xg = x + (size_t)(tok0 + row0) * RDIM + kq4;
    const float* wg = w + (size_t)row0 * RDIM + kq4;
    const int ldsoff = row0 * LDK + kq4;

    uint2 xh2[4], xl2[4], wh2[4], wl2[4];
    #pragma unroll
    for (int j = 0; j < 4; ++j) {          // chunk 0: load + convert
        float4 a = *(const float4*)(xg + (size_t)j * 16 * RDIM);
        float4 b = *(const float4*)(wg + (size_t)j * 16 * RDIM);
        split_pack(a, xh2[j].x, xh2[j].y, xl2[j].x, xl2[j].y);
        split_pack(b, wh2[j].x, wh2[j].y, wl2[j].x, wl2[j].y);
    }

    const int arow = tokG * 16 + l15;

    for (int c = 0; c < 4; ++c) {
        __syncthreads();                   // prior chunk's frag reads done
        #pragma unroll
        for (int j = 0; j < 4; ++j) {      // pure ds_write phase (converts done earlier)
            *(uint2*)&xhi[ldsoff + j * 16 * LDK] = xh2[j];
            *(uint2*)&xlo[ldsoff + j * 16 * LDK] = xl2[j];
            *(uint2*)&whi[ldsoff + j * 16 * LDK] = wh2[j];
            *(uint2*)&wlo[ldsoff + j * 16 * LDK] = wl2[j];
        }
        __syncthreads();
        float4 fa[4], fb[4];
        if (c < 3) {                       // issue next-chunk loads before compute
            const int o = (c + 1) * 128;
            #pragma unroll
            for (int j = 0; j < 4; ++j) {
                fa[j] = *(const float4*)(xg + o + (size_t)j * 16 * RDIM);
                fb[j] = *(const float4*)(wg + o + (size_t)j * 16 * RDIM);
            }
        }
        #pragma unroll
        for (int s = 0; s < 4; ++s) {      // 4 K32 steps per chunk
            const int kb = s * 32 + kgrp;
            s16x8 ah = *(const s16x8*)&xhi[arow * LDK + kb];
            s16x8 al = *(const s16x8*)&xlo[arow * LDK + kb];
            #pragma unroll
            for (int nt = 0; nt < 2; ++nt) {
                const int brow = expG * 32 + nt * 16 + l15;
                s16x8 bh = *(const s16x8*)&whi[brow * LDK + kb];
                s16x8 bl = *(const s16x8*)&wlo[brow * LDK + kb];
                acc[nt] = MFMA_B16(ah, bh, acc[nt]);   // hi*hi
                acc[nt] = MFMA_B16(ah, bl, acc[nt]);   // hi*lo
                acc[nt] = MFMA_B16(al, bh, acc[nt]);   // lo*hi
            }
        }
        if (c < 3) {                       // convert under the MFMA phase (VALU slots free)
            #pragma unroll
            for (int j = 0; j < 4; ++j) {
                split_pack(fa[j], xh2[j].x, xh2[j].y, xl2[j].x, xl2[j].y);
                split_pack(fb[j], wh2[j].x, wh2[j].y, wl2[j].x, wl2[j].y);
            }
        }
    }

    // ---- logits to LDS plane [64 tok][PSTR] ----
    __syncthreads();
    #pragma unroll
    for (int nt = 0; nt < 2; ++nt)
        #pragma unroll
        for (int i = 0; i < 4; ++i)
            P[(tokG * 16 + ((lane >> 4) << 2) + i) * PSTR + expG * 32 + nt * 16 + l15] = acc[nt][i];
    __syncthreads();

    // ---- E1: per (token tt, slice ss) local top-3 over 8 experts (no shuffles) ----
    const int tt = tid & 63;
    const int ss = tid >> 6;
    float v[8];
    #pragma unroll
    for (int j = 0; j < 8; ++j) v[j] = P[tt * PSTR + ss * 8 + j];

    float m1 = -INFINITY, m2 = -INFINITY, m3 = -INFINITY;
    int   i1 = NEXP, i2 = NEXP, i3 = NEXP;
    #pragma unroll
    for (int j = 0; j < 8; ++j) {          // ascending e + strict > == lax.top_k tie-break
        float val = v[j]; int e = ss * 8 + j;
        if (val > m1)      { m3 = m2; i3 = i2; m2 = m1; i2 = i1; m1 = val; i1 = e; }
        else if (val > m2) { m3 = m2; i3 = i2; m2 = val; i2 = e; }
        else if (val > m3) { m3 = val; i3 = e; }
    }
    candv[tt * 25 + ss * 3 + 0] = m1; candi[tt * 25 + ss * 3 + 0] = i1;
    candv[tt * 25 + ss * 3 + 1] = m2; candi[tt * 25 + ss * 3 + 1] = i2;
    candv[tt * 25 + ss * 3 + 2] = m3; candi[tt * 25 + ss * 3 + 2] = i3;
    __syncthreads();

    // ---- E2: merge 24 candidates (slice-ascending insertion keeps low-index ties first) ----
    m1 = m2 = m3 = -INFINITY; i1 = i2 = i3 = NEXP;
    #pragma unroll
    for (int q = 0; q < 24; ++q) {
        float val = candv[tt * 25 + q]; int e = candi[tt * 25 + q];
        if (val > m1)      { m3 = m2; i3 = i2; m2 = m1; i2 = i1; m1 = val; i1 = e; }
        else if (val > m2) { m3 = m2; i3 = i2; m2 = val; i2 = e; }
        else if (val > m3) { m3 = val; i3 = e; }
    }

    float ex[8]; float ps = 0.f;
    #pragma unroll
    for (int j = 0; j < 8; ++j) { ex[j] = __expf(v[j] - m1); ps += ex[j]; }
    qsum[tt * 9 + ss] = ps;

    if (ss == 0) {                         // gates (+ rare exact re-rank) once per token
        float g1v = m1, g2v = m2; int e1 = i1, e2 = i2;
        if (m2 - m3 < TAU) {
            const float* xrow = x + (size_t)(tok0 + tt) * RDIM;
            float d[3]; int id3[3] = { i1, i2, i3 };
            for (int jj = 0; jj < 3; ++jj) {
                const float* wrow = w + (size_t)id3[jj] * RDIM;
                float p = 0.f;
                #pragma unroll 4
                for (int k = 0; k < RDIM; k += 4) {
                    float4 a = *(const float4*)(xrow + k);
                    float4 b = *(const float4*)(wrow + k);
                    p = fmaf(a.x, b.x, p); p = fmaf(a.y, b.y, p);
                    p = fmaf(a.z, b.z, p); p = fmaf(a.w, b.w, p);
                }
                d[jj] = p;
            }
            int b = 0;
            if (d[1] > d[0] || (d[1] == d[0] && id3[1] < id3[0])) b = 1;
            if (d[2] > d[b] || (d[2] == d[b] && id3[2] < id3[b])) b = 2;
            int sec;
            if (b == 0)      sec = (d[1] > d[2] || (d[1] == d[2] && id3[1] < id3[2])) ? 1 : 2;
            else if (b == 1) sec = (d[0] > d[2] || (d[0] == d[2] && id3[0] < id3[2])) ? 0 : 2;
            else             sec = (d[0] > d[1] || (d[0] == d[1] && id3[0] < id3[1])) ? 0 : 1;
            g1v = d[b];   e1 = id3[b];
            g2v = d[sec]; e2 = id3[sec];
        }
        const float ed  = __expf(g2v - g1v);
        const float inv = 1.f / (1.f + ed);
        gateL[tt * 4 + 0] = inv;
        gateL[tt * 4 + 1] = ed * inv;
        ((int*)gateL)[tt * 4 + 2] = e1;
        ((int*)gateL)[tt * 4 + 3] = e2;
    }
    __syncthreads();

    // ---- E3: softmax denominator + probs in place ----
    float Z = 0.f;
    #pragma unroll
    for (int k = 0; k < 8; ++k) Z += qsum[tt * 9 + k];
    const float invZ = 1.f / Z;
    #pragma unroll
    for (int j = 0; j < 8; ++j) P[tt * PSTR + ss * 8 + j] = ex[j] * invZ;
    __syncthreads();

    // ---- E4: per-expert column sums for aux ----
    {
        const int e = tid & 63, tq = tid >> 6;
        float s = 0.f; unsigned cn = 0u;
        #pragma unroll
        for (int t = 0; t < 8; ++t) {
            float pv = P[(tq * 8 + t) * PSTR + e];
            s += pv; cn += (pv > 0.f) ? 1u : 0u;
        }
        atomicAdd(&s_aux[e], s);
        atomicAdd(&s_cnt[e], cn);
    }
    __syncthreads();
    if (tid < 64) {
        atomicAdd(aux_sum + tid, s_aux[tid]);
        atomicAdd(aux_cnt + tid, s_cnt[tid]);
    }

    // ---- OUT: wave handles 8 tokens, lane = r-chunk (coalesced 1KB stores) ----
    {
        const int e = lane;
        #pragma unroll
        for (int s2 = 0; s2 < 8; ++s2) {
            const int t2 = wave * 8 + s2;
            float4 g4 = *(float4*)&gateL[t2 * 4];       // broadcast read
            const float g1 = g4.x, g2 = g4.y;
            const int e1 = __float_as_int(g4.z), e2 = __float_as_int(g4.w);
            const float4* c1 = (const float4*)(cent + (size_t)e1 * RDIM);
            const float4* c2 = (const float4*)(cent + (size_t)e2 * RDIM);
            float4* op = (float4*)(out + (size_t)(tok0 + t2) * RDIM);
            float4 A0 = c1[e],      Bb0 = c2[e];
            float4 A1 = c1[e + 64], Bb1 = c2[e + 64];
            float4 o0, o1;
            o0.x = fmaf(g1, A0.x, g2 * Bb0.x); o0.y = fmaf(g1, A0.y, g2 * Bb0.y);
            o0.z = fmaf(g1, A0.z, g2 * Bb0.z); o0.w = fmaf(g1, A0.w, g2 * Bb0.w);
            o1.x = fmaf(g1, A1.x, g2 * Bb1.x); o1.y = fmaf(g1, A1.y, g2 * Bb1.y);
            o1.z = fmaf(g1, A1.z, g2 * Bb1.z); o1.w = fmaf(g1, A1.w, g2 * Bb1.w);
            op[e]      = o0;
            op[e + 64] = o1;
        }
    }
}

// ---------------- Kernel C: aux loss finalize ----------------
__global__ __launch_bounds__(64) void aux_kernel(
    const float* __restrict__ sums,
    const unsigned* __restrict__ cnts,
    float* __restrict__ out_aux)
{
    const int e = threadIdx.x;
    float v = (sums[e] * (1.f / (float)TOKENS)) * ((float)cnts[e] * (1.f / (float)TOKENS));
    #pragma unroll
    for (int off = 32; off; off >>= 1) v += __shfl_xor(v, off);
    if (e == 0) out_aux[0] = (float)NEXP * v;
}

extern "C" void kernel_launch(void* const* d_in, const int* in_sizes, int n_in,
                              void* d_out, int out_size, void* d_ws, size_t ws_size,
                              hipStream_t stream) {
    const float* x     = (const float*)d_in[0];  // (8,4096,512)
    const float* rw    = (const float*)d_in[1];  // (64,512)
    const float* atoms = (const float*)d_in[2];  // (64,16,512)
    const float* cwts  = (const float*)d_in[3];  // (64,256,3)
    const float* clog  = (const float*)d_in[4];  // (64,256,3,16)
    float* out = (float*)d_out;

    float*    aux_sum = (float*)d_ws;                       // 64 floats
    unsigned* aux_cnt = (unsigned*)((char*)d_ws + 256);     // 64 uints
    float*    cent    = (float*)((char*)d_ws + 512);        // 64*512 floats

    centroid_kernel<<<128, 256, 0, stream>>>(atoms, cwts, clog, cent, aux_sum, aux_cnt);
    moe_main<<<512, 512, 0, stream>>>(x, rw, cent, out, aux_sum, aux_cnt);
    aux_kernel<<<1, 64, 0, stream>>>(aux_sum, aux_cnt, out + (size_t)TOKENS * RDIM);
}

// Round 3
// 162.158 us; speedup vs baseline: 1.3169x; 1.0083x over previous
//
#include <hip/hip_runtime.h>
#include <math.h>

#define TOKENS 32768
#define RDIM 512
#define NEXP 64
#define NK 256
#define LDB 264            // w-plane LDS row stride in ushorts (256 + 8 pad); 528B rows -> 2-way banks (free)
#define PSTR 67            // logit plane row stride (words)
#define TAU 4.0e-3f        // top-2/3 boundary guard band (~60x worst-case bf16x3 logit error)

typedef unsigned short u16;
typedef float f32x4 __attribute__((ext_vector_type(4)));
typedef short s16x8 __attribute__((ext_vector_type(8)));

#define MFMA_B16(a, b, c) __builtin_amdgcn_mfma_f32_16x16x32_bf16(a, b, c, 0, 0, 0)

// Truncating hi/lo bf16 split of 4 floats, packed pairwise into uints (k-ascending).
__device__ __forceinline__ void split_pack(float4 v, unsigned& h01, unsigned& h23,
                                           unsigned& l01, unsigned& l23) {
    unsigned u0 = __float_as_uint(v.x), u1 = __float_as_uint(v.y);
    unsigned u2 = __float_as_uint(v.z), u3 = __float_as_uint(v.w);
    float r0 = v.x - __uint_as_float(u0 & 0xFFFF0000u);
    float r1 = v.y - __uint_as_float(u1 & 0xFFFF0000u);
    float r2 = v.z - __uint_as_float(u2 & 0xFFFF0000u);
    float r3 = v.w - __uint_as_float(u3 & 0xFFFF0000u);
    h01 = (u0 >> 16) | (u1 & 0xFFFF0000u);
    h23 = (u2 >> 16) | (u3 & 0xFFFF0000u);
    l01 = (__float_as_uint(r0) >> 16) | (__float_as_uint(r1) & 0xFFFF0000u);
    l23 = (__float_as_uint(r2) >> 16) | (__float_as_uint(r3) & 0xFFFF0000u);
}

// 8 floats -> bf16-hi frag + bf16-lo frag, in registers.
__device__ __forceinline__ void split8(float4 a, float4 b, s16x8& hi, s16x8& lo) {
    union U { unsigned u[4]; s16x8 v; };
    U H, L;
    split_pack(a, H.u[0], H.u[1], L.u[0], L.u[1]);
    split_pack(b, H.u[2], H.u[3], L.u[2], L.u[3]);
    hi = H.v; lo = L.v;
}

// ---------------- Kernel A: expert centroids via sign-LUT bit tricks (unchanged) ----------------
__global__ __launch_bounds__(256) void centroid_kernel(
    const float* __restrict__ atoms,
    const float* __restrict__ cw,
    const float* __restrict__ cl,
    float* __restrict__ cent,
    float* __restrict__ aux_sum,
    unsigned* __restrict__ aux_cnt)
{
    __shared__ unsigned pack[NK];
    const int e    = blockIdx.x >> 1;
    const int half = blockIdx.x & 1;
    const int tid  = threadIdx.x;

    if (blockIdx.x == 0 && tid < 64) { aux_sum[tid] = 0.f; aux_cnt[tid] = 0u; }

    {   // one k per thread (256 threads == NK)
        const int k = tid;
        unsigned u = 0;
        float w3[3];
        #pragma unroll
        for (int xx = 0; xx < 3; ++xx) {
            const float* cp = cl + ((((size_t)e * NK + k) * 3 + xx) << 4);
            float v[16];
            *(float4*)(v + 0)  = *(const float4*)(cp + 0);
            *(float4*)(v + 4)  = *(const float4*)(cp + 4);
            *(float4*)(v + 8)  = *(const float4*)(cp + 8);
            *(float4*)(v + 12) = *(const float4*)(cp + 12);
            float best = v[0]; int bi = 0;
            #pragma unroll
            for (int a = 1; a < 16; ++a) {          // strict > keeps first max (jnp.argmax)
                if (v[a] > best) { best = v[a]; bi = a; }
            }
            u |= (unsigned)bi << (4 * xx);
            w3[xx] = cw[((size_t)e * NK + k) * 3 + xx];
        }
        unsigned lut = 0;
        #pragma unroll
        for (int c = 0; c < 8; ++c) {
            float val = ((c & 1) ? -w3[0] : w3[0])
                      + ((c & 2) ? -w3[1] : w3[1])
                      + ((c & 4) ? -w3[2] : w3[2]);
            lut |= (val < 0.f ? 1u : 0u) << c;
        }
        pack[k] = u | (lut << 16);
    }

    const int r = half * 256 + tid;
    unsigned B0 = 0;
    #pragma unroll
    for (int a = 0; a < 16; ++a)
        B0 |= (atoms[((size_t)e * 16 + a) * RDIM + r] < 0.f ? 1u : 0u) << a;
    __syncthreads();

    int n0 = 0;
    for (int k = 0; k < NK; ++k) {
        unsigned u  = pack[k];
        unsigned i0 = u & 15u, i1 = (u >> 4) & 15u, i2 = (u >> 8) & 15u;
        unsigned c0 = ((B0 >> i0) & 1u) | (((B0 >> i1) & 1u) << 1) | (((B0 >> i2) & 1u) << 2);
        n0 += (u >> (16 + c0)) & 1u;
    }
    cent[(size_t)e * RDIM + r] = 1.f - (float)n0 * (1.f / 128.f);
}

// ---------------- Kernel B: barrier-free A-stream MFMA GEMM + MoE epilogue ----------------
// 512 threads = 8 waves, tile 64 tok x 64 exp. Wave (tokG=w>>1, expG=w&1) owns 16 tok x 32 exp.
// A-frags: loaded straight from global x as f32 (32B/lane; row-quads consume whole 64B lines),
// hi/lo-split in registers -> NO LDS, NO barriers on the A path, x read exactly once.
// B (w, 128KB L2-resident): bf16 hi/lo planes in LDS, staged once per K-half (2 stagings total).
// Verified MFMA mapping kept: A row=l15(token), B row=l15(expert), k=(lane>>4)*8+j;
// C col=lane&15, row=(lane>>4)*4+i.
__global__ __launch_bounds__(512, 4) void moe_main(
    const float* __restrict__ x,
    const float* __restrict__ w,
    const float* __restrict__ cent,
    float* __restrict__ out,
    float* __restrict__ aux_sum,
    unsigned* __restrict__ aux_cnt)
{
    __shared__ u16 wlds[2 * 64 * LDB];     // 67584 B: whi + wlo planes, one K-half at a time
    u16* whi = wlds;
    u16* wlo = wlds + 64 * LDB;
    // epilogue overlays (staging dead by then; 33.3KB used of 67.6KB)
    float* P     = (float*)wlds;           // [64][PSTR] logits -> probs in place
    float* candv = P + 64 * PSTR;          // [64][25] (8 slices x top-3, padded stride)
    int*   candi = (int*)(candv + 64 * 25);
    float* qsum  = (float*)(candi + 64 * 25);   // [64][9]
    float* gateL = qsum + 64 * 9;          // [64][4]: g1,g2,bitcast(e1),bitcast(e2)
    __shared__ float s_aux[64];
    __shared__ unsigned s_cnt[64];

    const int tid  = threadIdx.x;
    const int lane = tid & 63;
    const int wave = tid >> 6;
    const int l15  = lane & 15;
    const int kgrp = (lane >> 4) << 3;     // 0,8,16,24
    const int tok0 = blockIdx.x * 64;
    const int tokG = wave >> 1;            // 0..3
    const int expG = wave & 1;             // 0..1

    if (tid < 64) { s_aux[tid] = 0.f; s_cnt[tid] = 0u; }

    f32x4 acc[2];
    acc[0] = (f32x4){0.f,0.f,0.f,0.f};
    acc[1] = (f32x4){0.f,0.f,0.f,0.f};

    // A-path: lane's own token row + k-window base
    const float* xlane = x + (size_t)(tok0 + tokG * 16 + l15) * RDIM + kgrp;
    // w staging map: thread covers 32 floats of one expert row
    const int wrow = tid >> 3;             // 0..63
    const int wseg = tid & 7;              // 0..7
    const float* wg = w + (size_t)wrow * RDIM + wseg * 32;
    const int woff = wrow * LDB + wseg * 32;   // ushort offset

    for (int h = 0; h < 2; ++h) {
        // issue x prefetch (steps 0..2 of this half) before staging to hide latency under it
        const float* xb = xlane + h * 256;
        float4 p0a = *(const float4*)(xb);      float4 p0b = *(const float4*)(xb + 4);
        float4 p1a = *(const float4*)(xb + 32); float4 p1b = *(const float4*)(xb + 36);
        float4 p2a = *(const float4*)(xb + 64); float4 p2b = *(const float4*)(xb + 68);

        __syncthreads();                   // prior half's B-frag reads done
        #pragma unroll
        for (int j = 0; j < 8; ++j) {      // stage w K-half: f32 -> hi/lo planes
            float4 wv = *(const float4*)(wg + h * 256 + j * 4);
            unsigned h01, h23, l01, l23;
            split_pack(wv, h01, h23, l01, l23);
            *(uint2*)&whi[woff + j * 4] = make_uint2(h01, h23);
            *(uint2*)&wlo[woff + j * 4] = make_uint2(l01, l23);
        }
        __syncthreads();

        #pragma unroll
        for (int kb = 0; kb < 8; ++kb) {   // 8 K32 steps, barrier-free, 3-deep prefetch
            s16x8 ah, al;
            split8(p0a, p0b, ah, al);
            p0a = p1a; p0b = p1b; p1a = p2a; p1b = p2b;
            if (kb < 5) {
                const float* nx = xb + (kb + 3) * 32;
                p2a = *(const float4*)(nx);
                p2b = *(const float4*)(nx + 4);
            }
            const int kl = kb * 32 + kgrp;
            #pragma unroll
            for (int nt = 0; nt < 2; ++nt) {
                const int brow = expG * 32 + nt * 16 + l15;
                s16x8 bh = *(const s16x8*)&whi[brow * LDB + kl];
                s16x8 bl = *(const s16x8*)&wlo[brow * LDB + kl];
                acc[nt] = MFMA_B16(ah, bh, acc[nt]);   // hi*hi
                acc[nt] = MFMA_B16(ah, bl, acc[nt]);   // hi*lo
                acc[nt] = MFMA_B16(al, bh, acc[nt]);   // lo*hi
            }
        }
    }

    // ---- logits to LDS plane [64 tok][PSTR] ----
    __syncthreads();
    #pragma unroll
    for (int nt = 0; nt < 2; ++nt)
        #pragma unroll
        for (int i = 0; i < 4; ++i)
            P[(tokG * 16 + ((lane >> 4) << 2) + i) * PSTR + expG * 32 + nt * 16 + l15] = acc[nt][i];
    __syncthreads();

    // ---- E1: per (token tt, slice ss) local top-3 over 8 experts ----
    const int tt = tid & 63;
    const int ss = tid >> 6;
    float v[8];
    #pragma unroll
    for (int j = 0; j < 8; ++j) v[j] = P[tt * PSTR + ss * 8 + j];

    float m1 = -INFINITY, m2 = -INFINITY, m3 = -INFINITY;
    int   i1 = NEXP, i2 = NEXP, i3 = NEXP;
    #pragma unroll
    for (int j = 0; j < 8; ++j) {          // ascending e + strict > == lax.top_k tie-break
        float val = v[j]; int e = ss * 8 + j;
        if (val > m1)      { m3 = m2; i3 = i2; m2 = m1; i2 = i1; m1 = val; i1 = e; }
        else if (val > m2) { m3 = m2; i3 = i2; m2 = val; i2 = e; }
        else if (val > m3) { m3 = val; i3 = e; }
    }
    candv[tt * 25 + ss * 3 + 0] = m1; candi[tt * 25 + ss * 3 + 0] = i1;
    candv[tt * 25 + ss * 3 + 1] = m2; candi[tt * 25 + ss * 3 + 1] = i2;
    candv[tt * 25 + ss * 3 + 2] = m3; candi[tt * 25 + ss * 3 + 2] = i3;
    __syncthreads();

    // ---- E2: merge 24 candidates (slice-ascending insertion keeps low-index ties first) ----
    m1 = m2 = m3 = -INFINITY; i1 = i2 = i3 = NEXP;
    #pragma unroll
    for (int q = 0; q < 24; ++q) {
        float val = candv[tt * 25 + q]; int e = candi[tt * 25 + q];
        if (val > m1)      { m3 = m2; i3 = i2; m2 = m1; i2 = i1; m1 = val; i1 = e; }
        else if (val > m2) { m3 = m2; i3 = i2; m2 = val; i2 = e; }
        else if (val > m3) { m3 = val; i3 = e; }
    }

    float ex[8]; float ps = 0.f;
    #pragma unroll
    for (int j = 0; j < 8; ++j) { ex[j] = __expf(v[j] - m1); ps += ex[j]; }
    qsum[tt * 9 + ss] = ps;

    if (ss == 0) {                         // wave 0: gates + cooperative guard re-rank
        {   // default gates from MFMA logits
            const float ed  = __expf(m2 - m1);
            const float inv = 1.f / (1.f + ed);
            gateL[tt * 4 + 0] = inv;
            gateL[tt * 4 + 1] = ed * inv;
            ((int*)gateL)[tt * 4 + 2] = i1;
            ((int*)gateL)[tt * 4 + 3] = i2;
        }
        // near top-2/3 boundary: exact f32 re-rank, 64-lane cooperative per flagged token
        unsigned long long bmask = __ballot(m2 - m3 < TAU);
        while (bmask) {
            const int f = __ffsll(bmask) - 1;
            bmask &= bmask - 1;
            int id3[3];
            id3[0] = __shfl(i1, f); id3[1] = __shfl(i2, f); id3[2] = __shfl(i3, f);
            const float* xrow = x + (size_t)(tok0 + f) * RDIM + lane * 8;
            float4 a0 = *(const float4*)(xrow);
            float4 a1 = *(const float4*)(xrow + 4);
            float d[3];
            #pragma unroll
            for (int jj = 0; jj < 3; ++jj) {
                const float* wrow = w + (size_t)id3[jj] * RDIM + lane * 8;
                float4 b0 = *(const float4*)(wrow);
                float4 b1 = *(const float4*)(wrow + 4);
                float p = a0.x * b0.x;
                p = fmaf(a0.y, b0.y, p); p = fmaf(a0.z, b0.z, p); p = fmaf(a0.w, b0.w, p);
                p = fmaf(a1.x, b1.x, p); p = fmaf(a1.y, b1.y, p);
                p = fmaf(a1.z, b1.z, p); p = fmaf(a1.w, b1.w, p);
                #pragma unroll
                for (int off = 32; off; off >>= 1) p += __shfl_xor(p, off);
                d[jj] = p;
            }
            int b = 0;
            if (d[1] > d[0] || (d[1] == d[0] && id3[1] < id3[0])) b = 1;
            if (d[2] > d[b] || (d[2] == d[b] && id3[2] < id3[b])) b = 2;
            int sec;
            if (b == 0)      sec = (d[1] > d[2] || (d[1] == d[2] && id3[1] < id3[2])) ? 1 : 2;
            else if (b == 1) sec = (d[0] > d[2] || (d[0] == d[2] && id3[0] < id3[2])) ? 0 : 2;
            else             sec = (d[0] > d[1] || (d[0] == d[1] && id3[0] < id3[1])) ? 0 : 1;
            if (lane == f) {
                const float ed  = __expf(d[sec] - d[b]);
                const float inv = 1.f / (1.f + ed);
                gateL[f * 4 + 0] = inv;
                gateL[f * 4 + 1] = ed * inv;
                ((int*)gateL)[f * 4 + 2] = id3[b];
                ((int*)gateL)[f * 4 + 3] = id3[sec];
            }
        }
    }
    __syncthreads();

    // ---- E3: softmax denominator + probs in place ----
    float Z = 0.f;
    #pragma unroll
    for (int k = 0; k < 8; ++k) Z += qsum[tt * 9 + k];
    const float invZ = 1.f / Z;
    #pragma unroll
    for (int j = 0; j < 8; ++j) P[tt * PSTR + ss * 8 + j] = ex[j] * invZ;
    __syncthreads();

    // ---- E4: per-expert column sums for aux ----
    {
        const int e = tid & 63, tq = tid >> 6;
        float s = 0.f; unsigned cn = 0u;
        #pragma unroll
        for (int t = 0; t < 8; ++t) {
            float pv = P[(tq * 8 + t) * PSTR + e];
            s += pv; cn += (pv > 0.f) ? 1u : 0u;
        }
        atomicAdd(&s_aux[e], s);
        atomicAdd(&s_cnt[e], cn);
    }
    __syncthreads();
    if (tid < 64) {
        atomicAdd(aux_sum + tid, s_aux[tid]);
        atomicAdd(aux_cnt + tid, s_cnt[tid]);
    }

    // ---- OUT: wave handles 8 tokens, lane = r-chunk (coalesced 1KB stores) ----
    {
        const int e = lane;
        #pragma unroll
        for (int s2 = 0; s2 < 8; ++s2) {
            const int t2 = wave * 8 + s2;
            float4 g4 = *(float4*)&gateL[t2 * 4];       // broadcast read
            const float g1 = g4.x, g2 = g4.y;
            const int e1 = __float_as_int(g4.z), e2 = __float_as_int(g4.w);
            const float4* c1 = (const float4*)(cent + (size_t)e1 * RDIM);
            const float4* c2 = (const float4*)(cent + (size_t)e2 * RDIM);
            float4* op = (float4*)(out + (size_t)(tok0 + t2) * RDIM);
            float4 A0 = c1[e],      Bb0 = c2[e];
            float4 A1 = c1[e + 64], Bb1 = c2[e + 64];
            float4 o0, o1;
            o0.x = fmaf(g1, A0.x, g2 * Bb0.x); o0.y = fmaf(g1, A0.y, g2 * Bb0.y);
            o0.z = fmaf(g1, A0.z, g2 * Bb0.z); o0.w = fmaf(g1, A0.w, g2 * Bb0.w);
            o1.x = fmaf(g1, A1.x, g2 * Bb1.x); o1.y = fmaf(g1, A1.y, g2 * Bb1.y);
            o1.z = fmaf(g1, A1.z, g2 * Bb1.z); o1.w = fmaf(g1, A1.w, g2 * Bb1.w);
            op[e]      = o0;
            op[e + 64] = o1;
        }
    }
}

// ---------------- Kernel C: aux loss finalize ----------------
__global__ __launch_bounds__(64) void aux_kernel(
    const float* __restrict__ sums,
    const unsigned* __restrict__ cnts,
    float* __restrict__ out_aux)
{
    const int e = threadIdx.x;
    float v = (sums[e] * (1.f / (float)TOKENS)) * ((float)cnts[e] * (1.f / (float)TOKENS));
    #pragma unroll
    for (int off = 32; off; off >>= 1) v += __shfl_xor(v, off);
    if (e == 0) out_aux[0] = (float)NEXP * v;
}

extern "C" void kernel_launch(void* const* d_in, const int* in_sizes, int n_in,
                              void* d_out, int out_size, void* d_ws, size_t ws_size,
                              hipStream_t stream) {
    const float* x     = (const float*)d_in[0];  // (8,4096,512)
    const float* rw    = (const float*)d_in[1];  // (64,512)
    const float* atoms = (const float*)d_in[2];  // (64,16,512)
    const float* cwts  = (const float*)d_in[3];  // (64,256,3)
    const float* clog  = (const float*)d_in[4];  // (64,256,3,16)
    float* out = (float*)d_out;

    float*    aux_sum = (float*)d_ws;                       // 64 floats
    unsigned* aux_cnt = (unsigned*)((char*)d_ws + 256);     // 64 uints
    float*    cent    = (float*)((char*)d_ws + 512);        // 64*512 floats

    centroid_kernel<<<128, 256, 0, stream>>>(atoms, cwts, clog, cent, aux_sum, aux_cnt);
    moe_main<<<512, 512, 0, stream>>>(x, rw, cent, out, aux_sum, aux_cnt);
    aux_kernel<<<1, 64, 0, stream>>>(aux_sum, aux_cnt, out + (size_t)TOKENS * RDIM);
}